// Round 2
// baseline (2517.890 us; speedup 1.0000x reference)
//
#include <hip/hip_runtime.h>

// ---------------- degree / normalization ----------------
__global__ void init_deg(float* deg, int n) {
    int i = blockIdx.x * blockDim.x + threadIdx.x;
    if (i < n) deg[i] = 1.0f;  // self-loop weight
}

__global__ void deg_accum(const int* __restrict__ dst, const float* __restrict__ ew,
                          float* deg, int e) {
    int i = blockIdx.x * blockDim.x + threadIdx.x;
    if (i < e) atomicAdd(&deg[dst[i]], ew[i]);
}

__global__ void dinv_k(float* deg, int n) {
    int i = blockIdx.x * blockDim.x + threadIdx.x;
    if (i < n) {
        float d = deg[i];
        deg[i] = d > 0.0f ? rsqrtf(d) : 0.0f;
    }
}

// ---------------- dense linear: y[n,C] = x[n,K] @ W[K,C] ----------------
template <int K, int C>
__global__ void linear_k(const float* __restrict__ x, const float* __restrict__ W,
                         float* __restrict__ y, int n) {
    __shared__ float Ws[K * C];
    for (int i = threadIdx.x; i < K * C; i += blockDim.x) Ws[i] = W[i];
    __syncthreads();
    long gid = (long)blockIdx.x * blockDim.x + threadIdx.x;
    int node = (int)(gid / C);
    int c = (int)(gid % C);
    if (node >= n) return;
    const float* xr = x + (long)node * K;
    float acc = 0.0f;
#pragma unroll
    for (int k = 0; k < K; ++k) acc = fmaf(xr[k], Ws[k * C + c], acc);
    y[(long)node * C + c] = acc;
}

// ---------------- init accumulator with self-loop + bias: acc = dinv^2*xl + b ----------------
template <int C>
__global__ void init_self_k(const float* __restrict__ xl, const float* __restrict__ dinv,
                            const float* __restrict__ b, float* __restrict__ acc, int n) {
    long gid = (long)blockIdx.x * blockDim.x + threadIdx.x;
    int node = (int)(gid / C);
    int c = (int)(gid % C);
    if (node >= n) return;
    float di = dinv[node];
    acc[gid] = di * di * xl[gid] + b[c];
}

// ---------------- edge scatter: acc[dst] += norm * xl[src] ----------------
template <int C>
__global__ void scatter_k(const int* __restrict__ src, const int* __restrict__ dst,
                          const float* __restrict__ ew, const float* __restrict__ dinv,
                          const float* __restrict__ xl, float* __restrict__ acc, int e) {
    constexpr int VPT = C / 4;  // float4 groups per edge
    long gid = (long)blockIdx.x * blockDim.x + threadIdx.x;
    long edge = gid / VPT;
    int g = (int)(gid % VPT);
    if (edge >= e) return;
    int s = src[edge];
    int d = dst[edge];
    float w = dinv[s] * ew[edge] * dinv[d];
    float4 v = *reinterpret_cast<const float4*>(xl + (long)s * C + g * 4);
    float* o = acc + (long)d * C + g * 4;
    atomicAdd(o + 0, w * v.x);
    atomicAdd(o + 1, w * v.y);
    atomicAdd(o + 2, w * v.z);
    atomicAdd(o + 3, w * v.w);
}

// ---------------- in-place ReLU ----------------
__global__ void relu_k(float* a, long total) {
    long gid = (long)blockIdx.x * blockDim.x + threadIdx.x;
    if (gid < total) a[gid] = fmaxf(a[gid], 0.0f);
}

extern "C" void kernel_launch(void* const* d_in, const int* in_sizes, int n_in,
                              void* d_out, int out_size, void* d_ws, size_t ws_size,
                              hipStream_t stream) {
    const float* x = (const float*)d_in[0];
    const int* ei = (const int*)d_in[1];  // int64 in reference, delivered as int32
    const float* ew = (const float*)d_in[2];
    const float* W1 = (const float*)d_in[3];
    const float* b1 = (const float*)d_in[4];
    const float* W2 = (const float*)d_in[5];
    const float* b2 = (const float*)d_in[6];
    float* out = (float*)d_out;

    const int n = in_sizes[0] / 40;   // 100000
    const int e = in_sizes[2];        // 1600000
    const int* srcp = ei;             // edge_index[0]
    const int* dstp = ei + e;         // edge_index[1]

    // workspace layout (floats): dinv[n] | xl1[n*64] | acc1/h[n*64] | xl2[n*40]
    float* dinv = (float*)d_ws;
    float* xl1 = dinv + n;
    float* acc1 = xl1 + (long)n * 64;
    float* xl2 = acc1 + (long)n * 64;

    const int B = 256;
    auto cdiv = [](long a, long b) { return (int)((a + b - 1) / b); };

    // normalization (shared by both layers)
    init_deg<<<cdiv(n, B), B, 0, stream>>>(dinv, n);
    deg_accum<<<cdiv(e, B), B, 0, stream>>>(dstp, ew, dinv, e);
    dinv_k<<<cdiv(n, B), B, 0, stream>>>(dinv, n);

    // ---- layer 1: x[n,40] -> h[n,64] ----
    linear_k<40, 64><<<cdiv((long)n * 64, B), B, 0, stream>>>(x, W1, xl1, n);
    init_self_k<64><<<cdiv((long)n * 64, B), B, 0, stream>>>(xl1, dinv, b1, acc1, n);
    scatter_k<64><<<cdiv((long)e * 16, B), B, 0, stream>>>(srcp, dstp, ew, dinv, xl1, acc1, e);
    relu_k<<<cdiv((long)n * 64, B), B, 0, stream>>>(acc1, (long)n * 64);

    // ---- layer 2: h[n,64] -> out[n,40] ----
    linear_k<64, 40><<<cdiv((long)n * 40, B), B, 0, stream>>>(acc1, W2, xl2, n);
    init_self_k<40><<<cdiv((long)n * 40, B), B, 0, stream>>>(xl2, dinv, b2, out, n);
    scatter_k<40><<<cdiv((long)e * 10, B), B, 0, stream>>>(srcp, dstp, ew, dinv, xl2, out, e);
}

// Round 3
// 577.716 us; speedup vs baseline: 4.3584x; 4.3584x over previous
//
#include <hip/hip_runtime.h>

// ---------------- init: deg=1 (self-loop), cnt=0 ----------------
__global__ void init_k(float* deg, int* cnt, int n) {
    int i = blockIdx.x * blockDim.x + threadIdx.x;
    if (i < n) { deg[i] = 1.0f; cnt[i] = 0; }
}

// ---------------- per-edge: count + weighted degree ----------------
__global__ void count_deg_k(const int* __restrict__ dst, const float* __restrict__ ew,
                            float* deg, int* cnt, int e) {
    int i = blockIdx.x * blockDim.x + threadIdx.x;
    if (i < e) {
        int d = dst[i];
        atomicAdd(&deg[d], ew[i]);
        atomicAdd(&cnt[d], 1);
    }
}

__global__ void dinv_k(float* deg, int n) {
    int i = blockIdx.x * blockDim.x + threadIdx.x;
    if (i < n) {
        float d = deg[i];
        deg[i] = d > 0.0f ? rsqrtf(d) : 0.0f;
    }
}

// ---------------- scan step 1: per-2048-chunk exclusive scan ----------------
__global__ void scan1_k(const int* __restrict__ cnt, int* __restrict__ excl,
                        int* __restrict__ bsum, int n) {
    __shared__ int lds[256];
    int base = blockIdx.x * 2048;
    int pre[8];
    int tsum = 0;
#pragma unroll
    for (int j = 0; j < 8; ++j) {
        int idx = base + threadIdx.x * 8 + j;
        int v = (idx < n) ? cnt[idx] : 0;
        pre[j] = tsum;
        tsum += v;
    }
    lds[threadIdx.x] = tsum;
    __syncthreads();
    for (int off = 1; off < 256; off <<= 1) {
        int v = (threadIdx.x >= off) ? lds[threadIdx.x - off] : 0;
        __syncthreads();
        lds[threadIdx.x] += v;
        __syncthreads();
    }
    int texcl = lds[threadIdx.x] - tsum;
    if (threadIdx.x == 255) bsum[blockIdx.x] = lds[255];
#pragma unroll
    for (int j = 0; j < 8; ++j) {
        int idx = base + threadIdx.x * 8 + j;
        if (idx < n) excl[idx] = texcl + pre[j];
    }
}

// ---------------- scan step 2: serial exclusive scan of block sums ----------------
__global__ void scan2_k(int* bsum, int nb, int* rowptr_end, int e) {
    if (threadIdx.x == 0 && blockIdx.x == 0) {
        int run = 0;
        for (int i = 0; i < nb; ++i) {
            int v = bsum[i];
            bsum[i] = run;
            run += v;
        }
        *rowptr_end = e;  // row_ptr[n]
    }
}

// ---------------- scan step 3: add block offsets; produce rowptr + cursor ----------------
__global__ void scan3_k(int* __restrict__ rowptr, int* __restrict__ cursor,
                        const int* __restrict__ bsum, int n) {
    int i = blockIdx.x * blockDim.x + threadIdx.x;
    if (i < n) {
        int v = rowptr[i] + bsum[i >> 11];
        rowptr[i] = v;
        cursor[i] = v;
    }
}

// ---------------- CSR fill: col/src + normalized weight ----------------
__global__ void fill_csr_k(const int* __restrict__ src, const int* __restrict__ dst,
                           const float* __restrict__ ew, const float* __restrict__ dinv,
                           int* cursor, int* __restrict__ col, float* __restrict__ w, int e) {
    int i = blockIdx.x * blockDim.x + threadIdx.x;
    if (i < e) {
        int s = src[i], d = dst[i];
        int slot = atomicAdd(&cursor[d], 1);
        col[slot] = s;
        w[slot] = dinv[s] * ew[i] * dinv[d];
    }
}

// ---------------- dense linear: y[n,C] = x[n,K] @ W[K,C] ----------------
template <int K, int C>
__global__ void linear_k(const float* __restrict__ x, const float* __restrict__ W,
                         float* __restrict__ y, int n) {
    __shared__ float Ws[K * C];
    for (int i = threadIdx.x; i < K * C; i += blockDim.x) Ws[i] = W[i];
    __syncthreads();
    long gid = (long)blockIdx.x * blockDim.x + threadIdx.x;
    int node = (int)(gid / C);
    int c = (int)(gid % C);
    if (node >= n) return;
    const float* xr = x + (long)node * K;
    float acc = 0.0f;
#pragma unroll
    for (int k = 0; k < K; ++k) acc = fmaf(xr[k], Ws[k * C + c], acc);
    y[(long)node * C + c] = acc;
}

// ---------------- gather: one wave per node, lane = channel ----------------
template <int C, bool RELU>
__global__ void gather_k(const int* __restrict__ rowptr, const int* __restrict__ col,
                         const float* __restrict__ w, const float* __restrict__ xl,
                         const float* __restrict__ dinv, const float* __restrict__ b,
                         float* __restrict__ out, int n) {
    int node = (int)((long)blockIdx.x * blockDim.x + threadIdx.x) >> 6;
    int lane = threadIdx.x & 63;
    if (node >= n) return;
    int beg = rowptr[node];
    int end = rowptr[node + 1];
    if (lane >= C) return;
    float di = dinv[node];
    float acc = di * di * xl[(long)node * C + lane] + b[lane];
    int t = beg;
    // 2-deep manual pipeline for load latency
    for (; t + 1 < end; t += 2) {
        int s0 = col[t], s1 = col[t + 1];
        float w0 = w[t], w1 = w[t + 1];
        float v0 = xl[(long)s0 * C + lane];
        float v1 = xl[(long)s1 * C + lane];
        acc = fmaf(w0, v0, acc);
        acc = fmaf(w1, v1, acc);
    }
    if (t < end) {
        int s0 = col[t];
        acc = fmaf(w[t], xl[(long)s0 * C + lane], acc);
    }
    out[(long)node * C + lane] = RELU ? fmaxf(acc, 0.0f) : acc;
}

extern "C" void kernel_launch(void* const* d_in, const int* in_sizes, int n_in,
                              void* d_out, int out_size, void* d_ws, size_t ws_size,
                              hipStream_t stream) {
    const float* x = (const float*)d_in[0];
    const int* ei = (const int*)d_in[1];
    const float* ew = (const float*)d_in[2];
    const float* W1 = (const float*)d_in[3];
    const float* b1 = (const float*)d_in[4];
    const float* W2 = (const float*)d_in[5];
    const float* b2 = (const float*)d_in[6];
    float* out = (float*)d_out;

    const int n = in_sizes[0] / 40;   // 100000
    const int e = in_sizes[2];        // 1600000
    const int* srcp = ei;
    const int* dstp = ei + e;

    // ws layout (4B units):
    // dinv[n] | cnt/cursor[n] | rowptr[n+1] | bsum[64] | col[e] | wcsr[e] | xl1[n*64] | h[n*64]
    float* dinv = (float*)d_ws;
    int* cnt = (int*)(dinv + n);          // reused as cursor
    int* rowptr = cnt + n;
    int* bsum = rowptr + n + 1;
    int* col = bsum + 64;
    float* wcsr = (float*)(col + e);
    float* xl1 = wcsr + e;
    float* h = xl1 + (long)n * 64;
    float* xl2 = xl1;                     // overlay: xl1 dead after gather1

    const int B = 256;
    auto cdiv = [](long a, long b) { return (int)((a + b - 1) / b); };
    const int nb = cdiv(n, 2048);

    // ---- CSR build (shared by both layers) ----
    init_k<<<cdiv(n, B), B, 0, stream>>>(dinv, cnt, n);
    count_deg_k<<<cdiv(e, B), B, 0, stream>>>(dstp, ew, dinv, cnt, e);
    dinv_k<<<cdiv(n, B), B, 0, stream>>>(dinv, n);
    scan1_k<<<nb, 256, 0, stream>>>(cnt, rowptr, bsum, n);
    scan2_k<<<1, 64, 0, stream>>>(bsum, nb, rowptr + n, e);
    scan3_k<<<cdiv(n, B), B, 0, stream>>>(rowptr, cnt, bsum, n);
    fill_csr_k<<<cdiv(e, B), B, 0, stream>>>(srcp, dstp, ew, dinv, cnt, col, wcsr, e);

    // ---- layer 1: x[n,40] -> h[n,64] ----
    linear_k<40, 64><<<cdiv((long)n * 64, B), B, 0, stream>>>(x, W1, xl1, n);
    gather_k<64, true><<<cdiv((long)n * 64, B), B, 0, stream>>>(rowptr, col, wcsr, xl1, dinv, b1, h, n);

    // ---- layer 2: h[n,64] -> out[n,40] ----
    linear_k<64, 40><<<cdiv((long)n * 40, B), B, 0, stream>>>(h, W2, xl2, n);
    gather_k<40, false><<<cdiv((long)n * 64, B), B, 0, stream>>>(rowptr, col, wcsr, xl2, dinv, b2, out, n);
}

// Round 4
// 430.547 us; speedup vs baseline: 5.8481x; 1.3418x over previous
//
#include <hip/hip_runtime.h>

// fixed-point scale for weighted-degree accumulation (2^25)
#define FIX 33554432.0f
#define FIXINV (1.0f / 33554432.0f)

// ---------------- init packed deg/cnt: deg=1.0 (self-loop), cnt=0 ----------------
__global__ void init_k(unsigned long long* degcnt, int n) {
    int i = blockIdx.x * blockDim.x + threadIdx.x;
    if (i < n) degcnt[i] = (unsigned long long)(1u << 25);  // lo = 1.0 fixed-point
}

// ---------------- per-edge: single packed 64-bit atomic (count | weighted deg) ----------------
__global__ void count_deg_k(const int* __restrict__ dst, const float* __restrict__ ew,
                            unsigned long long* degcnt, int e) {
    int i = blockIdx.x * blockDim.x + threadIdx.x;
    if (i < e) {
        unsigned fx = __float2uint_rn(ew[i] * FIX);
        atomicAdd(&degcnt[dst[i]], (1ULL << 32) | (unsigned long long)fx);
    }
}

// ---------------- unpack: dinv = rsqrt(deg), cnt for scan ----------------
__global__ void dinv_k(const unsigned long long* __restrict__ degcnt,
                       float* __restrict__ dinv, int* __restrict__ cnt, int n) {
    int i = blockIdx.x * blockDim.x + threadIdx.x;
    if (i < n) {
        unsigned long long v = degcnt[i];
        cnt[i] = (int)(v >> 32);
        float d = (float)(unsigned)(v & 0xffffffffu) * FIXINV;  // >= 1.0 always
        dinv[i] = rsqrtf(d);
    }
}

// ---------------- scan step 1: per-2048-chunk exclusive scan ----------------
__global__ void scan1_k(const int* __restrict__ cnt, int* __restrict__ excl,
                        int* __restrict__ bsum, int n) {
    __shared__ int lds[256];
    int base = blockIdx.x * 2048;
    int pre[8];
    int tsum = 0;
#pragma unroll
    for (int j = 0; j < 8; ++j) {
        int idx = base + threadIdx.x * 8 + j;
        int v = (idx < n) ? cnt[idx] : 0;
        pre[j] = tsum;
        tsum += v;
    }
    lds[threadIdx.x] = tsum;
    __syncthreads();
    for (int off = 1; off < 256; off <<= 1) {
        int v = (threadIdx.x >= off) ? lds[threadIdx.x - off] : 0;
        __syncthreads();
        lds[threadIdx.x] += v;
        __syncthreads();
    }
    int texcl = lds[threadIdx.x] - tsum;
    if (threadIdx.x == 255) bsum[blockIdx.x] = lds[255];
#pragma unroll
    for (int j = 0; j < 8; ++j) {
        int idx = base + threadIdx.x * 8 + j;
        if (idx < n) excl[idx] = texcl + pre[j];
    }
}

// ---------------- scan step 2: serial exclusive scan of block sums ----------------
__global__ void scan2_k(int* bsum, int nb, int* rowptr_end, int e) {
    if (threadIdx.x == 0 && blockIdx.x == 0) {
        int run = 0;
        for (int i = 0; i < nb; ++i) {
            int v = bsum[i];
            bsum[i] = run;
            run += v;
        }
        *rowptr_end = e;
    }
}

// ---------------- scan step 3: add block offsets; produce rowptr + cursor ----------------
__global__ void scan3_k(int* __restrict__ rowptr, int* __restrict__ cursor,
                        const int* __restrict__ bsum, int n) {
    int i = blockIdx.x * blockDim.x + threadIdx.x;
    if (i < n) {
        int v = rowptr[i] + bsum[i >> 11];
        rowptr[i] = v;
        cursor[i] = v;
    }
}

// ---------------- CSR fill, 4 edges/thread for atomic-return latency hiding ----------------
__global__ void fill_csr_k(const int* __restrict__ src, const int* __restrict__ dst,
                           const float* __restrict__ ew, const float* __restrict__ dinv,
                           int* cursor, int* __restrict__ col, float* __restrict__ w, int e) {
    int base = (blockIdx.x * blockDim.x + threadIdx.x) * 4;
    if (base + 3 < e) {
        int s[4], d[4], slot[4];
        float wv[4];
#pragma unroll
        for (int j = 0; j < 4; ++j) { s[j] = src[base + j]; d[j] = dst[base + j]; }
#pragma unroll
        for (int j = 0; j < 4; ++j) wv[j] = dinv[s[j]] * ew[base + j] * dinv[d[j]];
#pragma unroll
        for (int j = 0; j < 4; ++j) slot[j] = atomicAdd(&cursor[d[j]], 1);
#pragma unroll
        for (int j = 0; j < 4; ++j) { col[slot[j]] = s[j]; w[slot[j]] = wv[j]; }
    } else {
        for (int i = base; i < e; ++i) {
            int s = src[i], d = dst[i];
            int slot = atomicAdd(&cursor[d], 1);
            col[slot] = s;
            w[slot] = dinv[s] * ew[i] * dinv[d];
        }
    }
}

// ---------------- dense linear: y[n,C] = x[n,K] @ W[K,C], optional bias+ReLU ----------------
template <int K, int C, bool BIAS_RELU>
__global__ void linear_k(const float* __restrict__ x, const float* __restrict__ W,
                         const float* __restrict__ b, float* __restrict__ y, int n) {
    __shared__ float Ws[K * C];
    for (int i = threadIdx.x; i < K * C; i += blockDim.x) Ws[i] = W[i];
    __syncthreads();
    long gid = (long)blockIdx.x * blockDim.x + threadIdx.x;
    int node = (int)(gid / C);
    int c = (int)(gid % C);
    if (node >= n) return;
    const float* xr = x + (long)node * K;
    float acc = 0.0f;
#pragma unroll
    for (int k = 0; k < K; ++k) acc = fmaf(xr[k], Ws[k * C + c], acc);
    if (BIAS_RELU) acc = fmaxf(acc + b[c], 0.0f);
    y[(long)node * C + c] = acc;
}

// ---------------- gather at C=40: wave per node, lane = channel ----------------
template <bool ADD_BIAS>
__global__ void gather40_k(const int* __restrict__ rowptr, const int* __restrict__ col,
                           const float* __restrict__ w, const float* __restrict__ feat,
                           const float* __restrict__ dinv, const float* __restrict__ b,
                           float* __restrict__ out, int n) {
    int node = (int)(((long)blockIdx.x * blockDim.x + threadIdx.x) >> 6);
    int lane = threadIdx.x & 63;
    if (node >= n) return;
    int beg = __builtin_amdgcn_readfirstlane(rowptr[node]);
    int end = __builtin_amdgcn_readfirstlane(rowptr[node + 1]);
    if (lane >= 40) return;
    float di = dinv[node];
    float acc = di * di * feat[(long)node * 40 + lane];
    if (ADD_BIAS) acc += b[lane];
    int t = beg;
    for (; t + 3 < end; t += 4) {
        int s0 = col[t], s1 = col[t + 1], s2 = col[t + 2], s3 = col[t + 3];
        float w0 = w[t], w1 = w[t + 1], w2 = w[t + 2], w3 = w[t + 3];
        float v0 = feat[(long)s0 * 40 + lane];
        float v1 = feat[(long)s1 * 40 + lane];
        float v2 = feat[(long)s2 * 40 + lane];
        float v3 = feat[(long)s3 * 40 + lane];
        acc = fmaf(w0, v0, acc);
        acc = fmaf(w1, v1, acc);
        acc = fmaf(w2, v2, acc);
        acc = fmaf(w3, v3, acc);
    }
    for (; t < end; ++t) acc = fmaf(w[t], feat[(long)col[t] * 40 + lane], acc);
    out[(long)node * 40 + lane] = acc;
}

extern "C" void kernel_launch(void* const* d_in, const int* in_sizes, int n_in,
                              void* d_out, int out_size, void* d_ws, size_t ws_size,
                              hipStream_t stream) {
    const float* x = (const float*)d_in[0];
    const int* ei = (const int*)d_in[1];
    const float* ew = (const float*)d_in[2];
    const float* W1 = (const float*)d_in[3];
    const float* b1 = (const float*)d_in[4];
    const float* W2 = (const float*)d_in[5];
    const float* b2 = (const float*)d_in[6];
    float* out = (float*)d_out;

    const int n = in_sizes[0] / 40;   // 100000
    const int e = in_sizes[2];        // 1600000
    const int* srcp = ei;
    const int* dstp = ei + e;

    // ws layout (4B units):
    // degcnt[2n] | dinv[n] | cnt[n] | rowptr[n+1] | bsum[64] | col[e] | wcsr[e] | agg1/xl2[n*40] | h[n*64]
    unsigned long long* degcnt = (unsigned long long*)d_ws;
    float* dinv = (float*)(degcnt + n);
    int* cnt = (int*)(dinv + n);          // reused as cursor
    int* rowptr = cnt + n;
    int* bsum = rowptr + n + 1;
    int* col = bsum + 64;
    float* wcsr = (float*)(col + e);
    float* agg1 = wcsr + e;               // layer-1 aggregated x [n,40]
    float* h = agg1 + (long)n * 40;       // hidden [n,64]
    float* xl2 = agg1;                    // overlay: agg1 dead after linear1

    const int B = 256;
    auto cdiv = [](long a, long b) { return (int)((a + b - 1) / b); };
    const int nb = cdiv(n, 2048);

    // ---- CSR build (shared by both layers) ----
    init_k<<<cdiv(n, B), B, 0, stream>>>(degcnt, n);
    count_deg_k<<<cdiv(e, B), B, 0, stream>>>(dstp, ew, degcnt, e);
    dinv_k<<<cdiv(n, B), B, 0, stream>>>(degcnt, dinv, cnt, n);
    scan1_k<<<nb, 256, 0, stream>>>(cnt, rowptr, bsum, n);
    scan2_k<<<1, 64, 0, stream>>>(bsum, nb, rowptr + n, e);
    scan3_k<<<cdiv(n, B), B, 0, stream>>>(rowptr, cnt, bsum, n);
    fill_csr_k<<<cdiv(e, (long)B * 4), B, 0, stream>>>(srcp, dstp, ew, dinv, cnt, col, wcsr, e);

    // ---- layer 1: agg1 = A_norm @ x (C=40), then h = relu(agg1 @ W1 + b1) ----
    gather40_k<false><<<cdiv((long)n * 64, B), B, 0, stream>>>(rowptr, col, wcsr, x, dinv, nullptr, agg1, n);
    linear_k<40, 64, true><<<cdiv((long)n * 64, B), B, 0, stream>>>(agg1, W1, b1, h, n);

    // ---- layer 2: xl2 = h @ W2 (C=40), then out = A_norm @ xl2 + b2 ----
    linear_k<64, 40, false><<<cdiv((long)n * 40, B), B, 0, stream>>>(h, W2, nullptr, xl2, n);
    gather40_k<true><<<cdiv((long)n * 64, B), B, 0, stream>>>(rowptr, col, wcsr, xl2, dinv, b2, out, n);
}